// Round 1
// 525.668 us; speedup vs baseline: 1.1962x; 1.1962x over previous
//
#include <hip/hip_runtime.h>
#include <hip/hip_bf16.h>
#include <math.h>

// ---------------------------------------------------------------------------
// Graft_StackedDense:
//   W0 = blend(w0, g0, p0)  [512,1024]   W1 = blend(w1, g1, p1)  [1,512]
//   out = relu(x @ W0^T + b0) @ W1^T + b1,  x:[65536,1024] fp32
//
// R2: main GEMM goes full-width: BM=64, BN=512 (all of H in accumulators),
// so x is read from HBM exactly ONCE (was 4x). Each block owns its 64 rows
// end-to-end: fused ReLU + W1 GEMV reduce in-block, direct store (+b1) —
// no out atomics, no init pass. blend0 rewritten as bf16 MFMA (256 blocks).
// hist rewritten with register bin counters (no LDS atomics).
// ---------------------------------------------------------------------------

typedef __attribute__((ext_vector_type(8))) short short8;
typedef __attribute__((ext_vector_type(4))) short short4v;
typedef __attribute__((ext_vector_type(4))) float floatx4;
typedef unsigned short ushort_t;

#define WS_ENT 0
#define WS_MM 4
#define WS_CNT 16
#define WS_W0B_WORD 64                    // bf16 W0b: 512*1024 ushorts = 262144 words
#define WS_W1B_WORD (64 + 262144)         // float W1b[512]

__device__ __forceinline__ unsigned f2ord(float f) {
    unsigned u = __float_as_uint(f);
    return (u & 0x80000000u) ? ~u : (u | 0x80000000u);
}
__device__ __forceinline__ float ord2f(unsigned k) {
    unsigned u = (k & 0x80000000u) ? (k ^ 0x80000000u) : ~k;
    return __uint_as_float(u);
}
__device__ __forceinline__ short f2bf(float f) {
    union { __hip_bfloat16 h; short s; } u;
    u.h = __float2bfloat16(f);
    return u.s;
}
__device__ __forceinline__ float blend_factor(float d, float wg) {
    float wl = 1.0f / (1.0f + expf(-d));
    float wb = wg * (1.0f - expf(-wg * wl));
    float wgr = (1.0f - wg) * (1.0f - expf(-(1.0f - wg) * (1.0f - wl)));
    return 1.0f / (1.0f + expf(-(wb - wgr)));
}
__device__ __forceinline__ float wglobal_from_ent(float eb, float eg) {
    return 0.12732395447351627f * atanf(500.0f * (eb - eg)) + 0.5f;
}
__device__ __forceinline__ void async16(const void* g, void* s) {
    __builtin_amdgcn_global_load_lds(
        (const __attribute__((address_space(1))) unsigned int*)g,
        (__attribute__((address_space(3))) unsigned int*)s, 16, 0, 0);
}

// ---------------------------------------------------------------------------
__global__ void init_ws(unsigned* ws_u) {
    int t = threadIdx.x;
    if (t < 4) {
        ws_u[WS_MM + 2 * t] = 0xFFFFFFFFu;
        ws_u[WS_MM + 2 * t + 1] = 0u;
    }
    if (t >= WS_CNT && t < WS_CNT + 40) ws_u[t] = 0u;
}

// ---------------------------------------------------------------------------
__device__ __forceinline__ void array_map(int bx, const float* w0, const float* g0,
                                          const float* w1, const float* g1,
                                          int& a, const float*& arr, int& per, int& start) {
    if (bx < 64) { a = 0; arr = w0; per = 524288 / 64; start = bx * per; }
    else if (bx < 128) { a = 1; arr = g0; per = 524288 / 64; start = (bx - 64) * per; }
    else if (bx == 128) { a = 2; arr = w1; per = 512; start = 0; }
    else { a = 3; arr = g1; per = 512; start = 0; }
}

__global__ __launch_bounds__(256) void minmax_kernel(const float* __restrict__ w0,
                                                     const float* __restrict__ g0,
                                                     const float* __restrict__ w1,
                                                     const float* __restrict__ g1,
                                                     unsigned* ws_u) {
    int a, per, start;
    const float* arr;
    array_map(blockIdx.x, w0, g0, w1, g1, a, arr, per, start);
    float mn = INFINITY, mx = -INFINITY;
    for (int i = threadIdx.x; i < per; i += 256) {
        float v = arr[start + i];
        mn = fminf(mn, v);
        mx = fmaxf(mx, v);
    }
#pragma unroll
    for (int off = 32; off > 0; off >>= 1) {
        mn = fminf(mn, __shfl_xor(mn, off));
        mx = fmaxf(mx, __shfl_xor(mx, off));
    }
    __shared__ float smn[4], smx[4];
    int wave = threadIdx.x >> 6, lane = threadIdx.x & 63;
    if (lane == 0) { smn[wave] = mn; smx[wave] = mx; }
    __syncthreads();
    if (threadIdx.x == 0) {
        mn = fminf(fminf(smn[0], smn[1]), fminf(smn[2], smn[3]));
        mx = fmaxf(fmaxf(smx[0], smx[1]), fmaxf(smx[2], smx[3]));
        atomicMin(&ws_u[WS_MM + 2 * a], f2ord(mn));
        atomicMax(&ws_u[WS_MM + 2 * a + 1], f2ord(mx));
    }
}

// Register-counter histogram: 10 unrolled compare-adds per element, no LDS atomics.
__global__ __launch_bounds__(256) void hist_kernel(const float* __restrict__ w0,
                                                   const float* __restrict__ g0,
                                                   const float* __restrict__ w1,
                                                   const float* __restrict__ g1,
                                                   unsigned* ws_u) {
    int a, per, start;
    const float* arr;
    array_map(blockIdx.x, w0, g0, w1, g1, a, arr, per, start);
    float lo = ord2f(ws_u[WS_MM + 2 * a]);
    float hi = ord2f(ws_u[WS_MM + 2 * a + 1]);
    float scale = __fdiv_rn(__fsub_rn(hi, lo), 10.0f);
    float lw[11];
#pragma unroll
    for (int j = 0; j < 11; j++)
        lw[j] = __fadd_rn(lo, __fmul_rn((float)j, scale));
    unsigned c[10];
#pragma unroll
    for (int b = 0; b < 10; b++) c[b] = 0u;
    for (int i = threadIdx.x; i < per; i += 256) {
        float v = arr[start + i];
#pragma unroll
        for (int b = 0; b < 10; b++)
            c[b] += (v >= lw[b] && v < lw[b + 1]) ? 1u : 0u;
    }
#pragma unroll
    for (int b = 0; b < 10; b++) {
#pragma unroll
        for (int off = 32; off > 0; off >>= 1) c[b] += __shfl_xor(c[b], off);
    }
    int lane = threadIdx.x & 63;
    if (lane == 0) {
#pragma unroll
        for (int b = 0; b < 10; b++)
            if (c[b] > 0u) atomicAdd(&ws_u[WS_CNT + a * 10 + b], c[b]);
    }
}

__global__ void finalize_ent_kernel(unsigned* ws_u) {
    int a = threadIdx.x;
    if (a < 4) {
        float n = (a < 2) ? 524288.0f : 512.0f;
        float ent = 0.0f;
        for (int i = 0; i < 10; i++) {
            float p = __fdiv_rn((float)ws_u[WS_CNT + a * 10 + i], n);
            if (p > 0.0f) ent = __fsub_rn(ent, __fmul_rn(p, logf(p)));
        }
        ((float*)ws_u)[WS_ENT + a] = ent;
    }
}

// ---------------------------------------------------------------------------
// W0 blend via bf16 MFMA: d[o,i] = sum_k |w0[o,k]-g0[o,k]| * p0[i,k].
// Tile 32(o) x 64(i), BK=32 -> grid (16,16) = 256 blocks, full GPU.
__global__ __launch_bounds__(256) void blend0_kernel(const float* __restrict__ w0,
                                                     const float* __restrict__ g0,
                                                     const float* __restrict__ p0,
                                                     const float* __restrict__ ws_f,
                                                     ushort_t* __restrict__ W0bb) {
    __shared__ ushort_t As[32 * 40];   // |w0-g0| tile, [o][k] pad 8
    __shared__ ushort_t Ps[64 * 40];   // p0 tile, [i][k] pad 8
    int tid = threadIdx.x;
    int w = tid >> 6, l = tid & 63;
    int bo = blockIdx.y * 32;   // o
    int bi = blockIdx.x * 64;   // i
    int wo = w & 1, wi = w >> 1;
    int m_in = l & 15, kq = l >> 4;

    floatx4 acc[2];
    const floatx4 zero = {0.0f, 0.0f, 0.0f, 0.0f};
    acc[0] = zero; acc[1] = zero;

    int ar = tid >> 3, ac = (tid & 7) * 4;   // A: 32x32 el, 4/thread
    int pr = tid >> 2, pc = (tid & 3) * 8;   // P: 64x32 el, 8/thread
    const float* wbase = w0 + (size_t)(bo + ar) * 1024 + ac;
    const float* gbase = g0 + (size_t)(bo + ar) * 1024 + ac;
    const float* pbase = p0 + (size_t)(bi + pr) * 1024 + pc;
    ushort_t* awr = &As[ar * 40 + ac];
    ushort_t* pwr = &Ps[pr * 40 + pc];

#pragma unroll 1
    for (int k0 = 0; k0 < 1024; k0 += 32) {
        float4 vw = *(const float4*)(wbase + k0);
        float4 vg = *(const float4*)(gbase + k0);
        float4 q0 = *(const float4*)(pbase + k0);
        float4 q1 = *(const float4*)(pbase + k0 + 4);
        short4v a4;
        a4[0] = f2bf(fabsf(vw.x - vg.x));
        a4[1] = f2bf(fabsf(vw.y - vg.y));
        a4[2] = f2bf(fabsf(vw.z - vg.z));
        a4[3] = f2bf(fabsf(vw.w - vg.w));
        short8 p8;
        p8[0] = f2bf(q0.x); p8[1] = f2bf(q0.y); p8[2] = f2bf(q0.z); p8[3] = f2bf(q0.w);
        p8[4] = f2bf(q1.x); p8[5] = f2bf(q1.y); p8[6] = f2bf(q1.z); p8[7] = f2bf(q1.w);
        *(short4v*)awr = a4;
        *(short8*)pwr = p8;
        __syncthreads();
        short8 af = *(const short8*)&As[(wo * 16 + m_in) * 40 + kq * 8];
        short8 pf0 = *(const short8*)&Ps[(wi * 32 + m_in) * 40 + kq * 8];
        short8 pf1 = *(const short8*)&Ps[(wi * 32 + 16 + m_in) * 40 + kq * 8];
        acc[0] = __builtin_amdgcn_mfma_f32_16x16x32_bf16(af, pf0, acc[0], 0, 0, 0);
        acc[1] = __builtin_amdgcn_mfma_f32_16x16x32_bf16(af, pf1, acc[1], 0, 0, 0);
        __syncthreads();
    }
    float wg = wglobal_from_ent(ws_f[WS_ENT + 0], ws_f[WS_ENT + 1]);
#pragma unroll
    for (int tn = 0; tn < 2; tn++) {
#pragma unroll
        for (int reg = 0; reg < 4; reg++) {
            int o = bo + wo * 16 + kq * 4 + reg;
            int i = bi + wi * 32 + tn * 16 + m_in;
            float s0 = blend_factor(acc[tn][reg], wg);
            float v = w0[o * 1024 + i] * s0 + g0[o * 1024 + i] * (1.0f - s0);
            W0bb[o * 1024 + i] = (ushort_t)f2bf(v);
        }
    }
}

// W1 blend (fp32, tiny)
__global__ __launch_bounds__(256) void blend1_kernel(const float* __restrict__ w1,
                                                     const float* __restrict__ g1,
                                                     const float* __restrict__ p1,
                                                     const float* __restrict__ ws_f,
                                                     float* __restrict__ W1b) {
    __shared__ float diff[512];
    int tid = threadIdx.x;
    for (int i = tid; i < 512; i += 256) diff[i] = fabsf(w1[i] - g1[i]);
    __syncthreads();
    int wave = tid >> 6, lane = tid & 63;
    int i = blockIdx.x * 4 + wave;
    float acc = 0.0f;
#pragma unroll
    for (int j = 0; j < 8; j++) {
        int k = lane + 64 * j;
        acc += diff[k] * p1[i * 512 + k];
    }
#pragma unroll
    for (int off = 32; off > 0; off >>= 1) acc += __shfl_xor(acc, off);
    if (lane == 0) {
        float wg = wglobal_from_ent(ws_f[WS_ENT + 2], ws_f[WS_ENT + 3]);
        float s0 = blend_factor(acc, wg);
        W1b[i] = w1[i] * s0 + g1[i] * (1.0f - s0);
    }
}

// ---------------------------------------------------------------------------
// Main MFMA kernel. Block = 64(M) x 512(N = all of H), BK=32, 256 threads.
// 4 waves side by side in N: wave w covers h in [w*128, w*128+128).
// x read from HBM exactly once. Epilogue reduces over ALL of H in-block:
// direct store of out rows (+b1), no atomics.
__global__ __launch_bounds__(256, 2) void main_mfma(const float* __restrict__ x,
                                                    const float* __restrict__ b0,
                                                    const ushort_t* __restrict__ W0bb,
                                                    const float* __restrict__ W1b,
                                                    const float* __restrict__ b1,
                                                    float* __restrict__ out) {
    __shared__ ushort_t As[64 * 40];    // [row][k] bf16, row stride 40 (pad 8)
    __shared__ ushort_t Bs[512 * 32];   // [h][k] bf16, linear (global_load_lds)
    __shared__ float red[4][64];
    int tid = threadIdx.x;
    int w = tid >> 6, l = tid & 63;
    int row0 = blockIdx.x * 64;
    int m_in = l & 15, kq = l >> 4;

    floatx4 acc[4][8];
    const floatx4 zero = {0.0f, 0.0f, 0.0f, 0.0f};
#pragma unroll
    for (int tm = 0; tm < 4; tm++)
#pragma unroll
        for (int tn = 0; tn < 8; tn++) acc[tm][tn] = zero;

    // A staging: thread t -> row t>>2 (0..63), k-chunk (t&3)*8 (8 floats)
    int arow = tid >> 2, acol = (tid & 3) * 8;
    const float* xbase = x + (size_t)(row0 + arow) * 1024 + acol;
    ushort_t* awr = &As[arow * 40 + acol];
    // B staging: instr r (0..7): lane l -> h = r*64 + w*16 + (l>>2), kc = (l&3)*8
    const ushort_t* bsrc = W0bb + (size_t)(w * 16 + (l >> 2)) * 1024 + (l & 3) * 8;
    ushort_t* bdst = &Bs[w * 512];

    // A prefetch (T14): regs hold tile k0 while tile k0+32 streams in.
    float4 pv0 = *(const float4*)(xbase);
    float4 pv1 = *(const float4*)(xbase + 4);

#pragma unroll 1
    for (int k0 = 0; k0 < 1024; k0 += 32) {
        // B: 32KB tile (all 512 h), 8 x global_load_lds width-16 per thread
#pragma unroll
        for (int r = 0; r < 8; r++)
            async16(bsrc + r * 65536 + k0, bdst + r * 2048);
        // A: cvt the prefetched 8 floats -> bf16, one ds_write_b128
        short8 s0;
        s0[0] = f2bf(pv0.x); s0[1] = f2bf(pv0.y); s0[2] = f2bf(pv0.z); s0[3] = f2bf(pv0.w);
        s0[4] = f2bf(pv1.x); s0[5] = f2bf(pv1.y); s0[6] = f2bf(pv1.z); s0[7] = f2bf(pv1.w);
        *(short8*)awr = s0;
        int kn = (k0 + 32 < 1024) ? k0 + 32 : 0;   // clamped dummy on last iter
        __syncthreads();   // drains vmcnt (async B) + lgkm (A writes)
        // issue next A tile loads; latency hides under frag reads + MFMA
        pv0 = *(const float4*)(xbase + kn);
        pv1 = *(const float4*)(xbase + kn + 4);
        short8 af[4];
#pragma unroll
        for (int tm = 0; tm < 4; tm++)
            af[tm] = *(const short8*)&As[(tm * 16 + m_in) * 40 + kq * 8];
#pragma unroll
        for (int tn = 0; tn < 8; tn++) {
            short8 bfr = *(const short8*)&Bs[(w * 128 + tn * 16 + m_in) * 32 + kq * 8];
#pragma unroll
            for (int tm = 0; tm < 4; tm++)
                acc[tm][tn] = __builtin_amdgcn_mfma_f32_16x16x32_bf16(
                    af[tm], bfr, acc[tm][tn], 0, 0, 0);
        }
        __syncthreads();   // protect LDS before next staging
    }

    // epilogue: rows = row0 + tm*16 + kq*4 + reg; cols h = w*128 + tn*16 + m_in
    float b0v[8], w1v[8];
#pragma unroll
    for (int tn = 0; tn < 8; tn++) {
        int h = w * 128 + tn * 16 + m_in;
        b0v[tn] = b0[h];
        w1v[tn] = W1b[h];
    }
#pragma unroll
    for (int tm = 0; tm < 4; tm++) {
#pragma unroll
        for (int reg = 0; reg < 4; reg++) {
            float s = 0.0f;
#pragma unroll
            for (int tn = 0; tn < 8; tn++) {
                float y = acc[tm][tn][reg] + b0v[tn];
                y = fmaxf(y, 0.0f);
                s += y * w1v[tn];
            }
            s += __shfl_xor(s, 1);
            s += __shfl_xor(s, 2);
            s += __shfl_xor(s, 4);
            s += __shfl_xor(s, 8);
            if (m_in == 0) red[w][tm * 16 + kq * 4 + reg] = s;
        }
    }
    __syncthreads();
    if (tid < 64)
        out[row0 + tid] = red[0][tid] + red[1][tid] + red[2][tid] + red[3][tid] + b1[0];
}

// ---------------------------------------------------------------------------
extern "C" void kernel_launch(void* const* d_in, const int* in_sizes, int n_in,
                              void* d_out, int out_size, void* d_ws, size_t ws_size,
                              hipStream_t stream) {
    const float* x = (const float*)d_in[0];
    const float* w0 = (const float*)d_in[1];
    const float* b0 = (const float*)d_in[2];
    const float* w1 = (const float*)d_in[3];
    const float* b1 = (const float*)d_in[4];
    const float* p0 = (const float*)d_in[5];
    const float* p1 = (const float*)d_in[6];
    const float* g0 = (const float*)d_in[7];
    const float* g1 = (const float*)d_in[8];
    float* out = (float*)d_out;
    unsigned* ws_u = (unsigned*)d_ws;
    float* ws_f = (float*)d_ws;
    ushort_t* W0bb = (ushort_t*)(ws_u + WS_W0B_WORD);
    float* W1b = ws_f + WS_W1B_WORD;

    init_ws<<<1, 64, 0, stream>>>(ws_u);
    minmax_kernel<<<130, 256, 0, stream>>>(w0, g0, w1, g1, ws_u);
    hist_kernel<<<130, 256, 0, stream>>>(w0, g0, w1, g1, ws_u);
    finalize_ent_kernel<<<1, 64, 0, stream>>>(ws_u);
    blend0_kernel<<<dim3(16, 16), 256, 0, stream>>>(w0, g0, p0, ws_f, W0bb);
    blend1_kernel<<<128, 256, 0, stream>>>(w1, g1, p1, ws_f, W1b);
    main_mfma<<<1024, 256, 0, stream>>>(x, b0, W0bb, W1b, b1, out);
}